// Round 1
// 701.959 us; speedup vs baseline: 1.0079x; 1.0079x over previous
//
#include <hip/hip_runtime.h>
#include <hip/hip_fp16.h>
#include <math.h>

#define TAU_INV 5.0f   // 1 / 0.2

typedef _Float16 half2v __attribute__((ext_vector_type(2)));

// ---------------------------------------------------------------------------
__device__ __forceinline__ void atomicMaxFloat(float* addr, float val) {
    if (val >= 0.0f) {
        atomicMax((int*)addr, __float_as_int(val));
    } else {
        atomicMin((unsigned int*)addr, __float_as_uint(val));
    }
}

__global__ void init_seg(float* __restrict__ seg_max, float* __restrict__ seg_sum, int n) {
    int i = blockIdx.x * blockDim.x + threadIdx.x;
    if (i < n) {
        seg_max[i] = -INFINITY;
        seg_sum[i] = 0.0f;
    }
}

// ---------------------------------------------------------------------------
// Merged fp32 GEMM (R5 structure — known 147 us; do NOT hand-pipeline: R4's
// serial register stream and R6's cross-barrier prefetch regs both lost).
// X = [Xu; Xi] (75000 x 256); Q = X@Wq+bq, K = X@Wk+bk; A staged once.
// Epilogue: fp16 INTERLEAVED rows  QK[gr*256 + 0..127] = Q, [128..255] = K.
// ---------------------------------------------------------------------------
__global__ __launch_bounds__(256) void gemm_qk_merged(
    const float* __restrict__ Xu, const float* __restrict__ Xi,
    const float* __restrict__ Wq, const float* __restrict__ bq,
    const float* __restrict__ Wk, const float* __restrict__ bk,
    __half* __restrict__ QK,
    int U, int I, int D)
{
    __shared__ float As_t[16][68];
    __shared__ float Bs_q[16][132];
    __shared__ float Bs_k[16][132];

    const int tid  = threadIdx.x;
    const int row0 = blockIdx.x * 64;
    const int tr   = tid >> 5;
    const int tc   = tid & 31;

    float4 accq[8], acck[8];
#pragma unroll
    for (int i = 0; i < 8; ++i) {
        accq[i] = make_float4(0.f, 0.f, 0.f, 0.f);
        acck[i] = make_float4(0.f, 0.f, 0.f, 0.f);
    }

    const int ar  = tid >> 2;
    const int akq = (tid & 3) * 4;

    for (int k0 = 0; k0 < D; k0 += 16) {
        {
            int gr = row0 + ar;
            float4 v = make_float4(0.f, 0.f, 0.f, 0.f);
            if (gr < U)            v = *(const float4*)&Xu[(size_t)gr * D + k0 + akq];
            else if (gr - U < I)   v = *(const float4*)&Xi[(size_t)(gr - U) * D + k0 + akq];
            As_t[akq + 0][ar] = v.x;
            As_t[akq + 1][ar] = v.y;
            As_t[akq + 2][ar] = v.z;
            As_t[akq + 3][ar] = v.w;
        }
#pragma unroll
        for (int t = 0; t < 2; ++t) {
            int idx = tid + t * 256;
            int r  = idx >> 5;
            int c4 = (idx & 31) * 4;
            float4 vq = *(const float4*)&Wq[(size_t)(k0 + r) * 128 + c4];
            float4 vk = *(const float4*)&Wk[(size_t)(k0 + r) * 128 + c4];
            *(float4*)&Bs_q[r][c4] = vq;
            *(float4*)&Bs_k[r][c4] = vk;
        }
        __syncthreads();

#pragma unroll
        for (int kk = 0; kk < 16; ++kk) {
            float4 a0  = *(const float4*)&As_t[kk][tr * 8];
            float4 a1  = *(const float4*)&As_t[kk][tr * 8 + 4];
            float4 bqv = *(const float4*)&Bs_q[kk][tc * 4];
            float4 bkv = *(const float4*)&Bs_k[kk][tc * 4];
            float a[8] = {a0.x, a0.y, a0.z, a0.w, a1.x, a1.y, a1.z, a1.w};
#pragma unroll
            for (int i = 0; i < 8; ++i) {
                accq[i].x += a[i] * bqv.x;
                accq[i].y += a[i] * bqv.y;
                accq[i].z += a[i] * bqv.z;
                accq[i].w += a[i] * bqv.w;
                acck[i].x += a[i] * bkv.x;
                acck[i].y += a[i] * bkv.y;
                acck[i].z += a[i] * bkv.z;
                acck[i].w += a[i] * bkv.w;
            }
        }
        __syncthreads();
    }

    const float4 bbq = *(const float4*)&bq[tc * 4];
    const float4 bbk = *(const float4*)&bk[tc * 4];
    const int NT = U + I;
#pragma unroll
    for (int i = 0; i < 8; ++i) {
        int gr = row0 + tr * 8 + i;
        if (gr < NT) {
            __half2 q01 = __floats2half2_rn(accq[i].x + bbq.x, accq[i].y + bbq.y);
            __half2 q23 = __floats2half2_rn(accq[i].z + bbq.z, accq[i].w + bbq.w);
            __half2 k01 = __floats2half2_rn(acck[i].x + bbk.x, acck[i].y + bbk.y);
            __half2 k23 = __floats2half2_rn(acck[i].z + bbk.z, acck[i].w + bbk.w);
            uint2 pq, pk;
            pq.x = *(const unsigned int*)&q01;
            pq.y = *(const unsigned int*)&q23;
            pk.x = *(const unsigned int*)&k01;
            pk.y = *(const unsigned int*)&k23;
            *(uint2*)&QK[(size_t)gr * 256 + tc * 4]       = pq;   // Q half
            *(uint2*)&QK[(size_t)gr * 256 + 128 + tc * 4] = pk;   // K half
        }
    }
}

// ---------------------------------------------------------------------------
// Fused BOTH-direction edge kernel. 32 lanes per edge:
//   lanes 0-15  (g=0): w_ui = Q_user[r] . K_item[c], seg = r,     out[eid]
//   lanes 16-31 (g=1): w_iu = Q_item[c] . K_user[r], seg = U + c, out[E+eid]
// Dot product via v_dot2_f32_f16 (fp16 pair-dot, fp32 accumulate): 4 insts
// per lane instead of 16 cvt + 8 fma.
// ---------------------------------------------------------------------------
__global__ __launch_bounds__(256) void edge_w_both(
    const __half* __restrict__ QK,
    const int* __restrict__ rows, const int* __restrict__ cols,
    const float* __restrict__ noise_ui, const float* __restrict__ noise_iu,
    float* __restrict__ out, float* __restrict__ seg_max, int U, int E)
{
    const int gtid = blockIdx.x * 256 + threadIdx.x;
    const int eid  = gtid >> 5;
    if (eid >= E) return;
    const int l  = threadIdx.x & 31;
    const int g  = l >> 4;        // 0 = ui, 1 = iu
    const int hl = l & 15;

    const int r = rows[eid];
    const int c = cols[eid];
    const __half* urow = QK + (size_t)r * 256;
    const __half* irow = QK + (size_t)(U + c) * 256;
    const __half* qrow = g ? irow : urow;
    const __half* krow = g ? urow : irow;

    const uint4 qp = *(const uint4*)(qrow + hl * 8);
    const uint4 kp = *(const uint4*)(krow + 128 + hl * 8);

    float d = 0.0f;
#if defined(__has_builtin) && __has_builtin(__builtin_amdgcn_fdot2)
    {
        const half2v* qh = (const half2v*)&qp;
        const half2v* kh = (const half2v*)&kp;
#pragma unroll
        for (int t = 0; t < 4; ++t)
            d = __builtin_amdgcn_fdot2(qh[t], kh[t], d, false);
    }
#else
    {
        const __half2* qh = (const __half2*)&qp;
        const __half2* kh = (const __half2*)&kp;
#pragma unroll
        for (int t = 0; t < 4; ++t) {
            float2 a = __half22float2(qh[t]);
            float2 b = __half22float2(kh[t]);
            d += a.x * b.x + a.y * b.y;
        }
    }
#endif
    d += __shfl_xor(d, 8);
    d += __shfl_xor(d, 4);
    d += __shfl_xor(d, 2);
    d += __shfl_xor(d, 1);

    if (hl == 0) {
        float nz = g ? noise_iu[eid] : noise_ui[eid];
        float zz = (d - __logf(-__logf(nz))) * TAU_INV;
        int s = g ? (U + c) : r;
        out[(size_t)g * E + eid] = zz;
        atomicMaxFloat(&seg_max[s], zz);
    }
}

// ---------------------------------------------------------------------------
// e = exp(z - max[seg]) stored in-place; atomic segment sum.
// Vectorized: 2 elements per thread (requires E even so pairs never straddle
// the region boundary at E and stay 8B-aligned).
// ---------------------------------------------------------------------------
__global__ void edge_exp2v(float* __restrict__ z,
                           const int* __restrict__ rows, const int* __restrict__ cols,
                           const float* __restrict__ seg_max,
                           float* __restrict__ seg_sum, int U, int E)
{
    int p = blockIdx.x * blockDim.x + threadIdx.x;
    int i = p * 2;
    if (i >= 2 * E) return;
    const bool iu  = (i >= E);
    const int base = iu ? (i - E) : i;
    const int off  = iu ? U : 0;
    const int* idx = iu ? cols : rows;
    int2 rc   = *(const int2*)&idx[base];
    float2 zz = *(const float2*)&z[i];
    int s0 = off + rc.x;
    int s1 = off + rc.y;
    float e0 = __expf(zz.x - seg_max[s0]);
    float e1 = __expf(zz.y - seg_max[s1]);
    *(float2*)&z[i] = make_float2(e0, e1);
    atomicAdd(&seg_sum[s0], e0);
    atomicAdd(&seg_sum[s1], e1);
}

__global__ void edge_exp2(float* __restrict__ z,
                          const int* __restrict__ rows, const int* __restrict__ cols,
                          const float* __restrict__ seg_max,
                          float* __restrict__ seg_sum, int U, int E)
{
    int i = blockIdx.x * blockDim.x + threadIdx.x;
    if (i >= 2 * E) return;
    int s = (i < E) ? rows[i] : (U + cols[i - E]);
    float e = __expf(z[i] - seg_max[s]);
    z[i] = e;
    atomicAdd(&seg_sum[s], e);
}

// ---------------------------------------------------------------------------
// out = e / sum[seg]
// ---------------------------------------------------------------------------
__global__ void edge_norm2v(float* __restrict__ ev,
                            const int* __restrict__ rows, const int* __restrict__ cols,
                            const float* __restrict__ seg_sum, int U, int E)
{
    int p = blockIdx.x * blockDim.x + threadIdx.x;
    int i = p * 2;
    if (i >= 2 * E) return;
    const bool iu  = (i >= E);
    const int base = iu ? (i - E) : i;
    const int off  = iu ? U : 0;
    const int* idx = iu ? cols : rows;
    int2 rc   = *(const int2*)&idx[base];
    float2 ee = *(const float2*)&ev[i];
    ee.x = ee.x / seg_sum[off + rc.x];
    ee.y = ee.y / seg_sum[off + rc.y];
    *(float2*)&ev[i] = ee;
}

__global__ void edge_norm2(float* __restrict__ ev,
                           const int* __restrict__ rows, const int* __restrict__ cols,
                           const float* __restrict__ seg_sum, int U, int E)
{
    int i = blockIdx.x * blockDim.x + threadIdx.x;
    if (i >= 2 * E) return;
    int s = (i < E) ? rows[i] : (U + cols[i - E]);
    ev[i] = ev[i] / seg_sum[s];
}

// ---------------------------------------------------------------------------
extern "C" void kernel_launch(void* const* d_in, const int* in_sizes, int n_in,
                              void* d_out, int out_size, void* d_ws, size_t ws_size,
                              hipStream_t stream)
{
    const float* user_embed = (const float*)d_in[0];
    const float* item_embed = (const float*)d_in[1];
    const float* Wq = (const float*)d_in[2];
    const float* bq = (const float*)d_in[3];
    const float* Wk = (const float*)d_in[4];
    const float* bk = (const float*)d_in[5];
    const int* ui_rows    = (const int*)d_in[6];
    const int* ui_cols    = (const int*)d_in[7];
    const float* noise_ui = (const float*)d_in[8];
    const float* noise_iu = (const float*)d_in[9];

    const int H = in_sizes[3];           // 128
    const int D = in_sizes[2] / H;       // 256
    const int U = in_sizes[0] / D;       // 50000
    const int I = in_sizes[1] / D;       // 25000
    const int E = in_sizes[6];           // 1600000

    const int nseg = U + I;

    // workspace: QK (fp16 interleaved, (U+I) x 256) | seg_max | seg_sum
    char* wsc = (char*)d_ws;
    __half* QK = (__half*)wsc;        wsc += (size_t)nseg * 256 * sizeof(__half);
    float* seg_max = (float*)wsc;     wsc += (size_t)nseg * sizeof(float);
    float* seg_sum = (float*)wsc;     wsc += (size_t)nseg * sizeof(float);

    float* out = (float*)d_out;       // [z_ui | z_iu] -> e -> normalized, in place

    init_seg<<<(nseg + 255) / 256, 256, 0, stream>>>(seg_max, seg_sum, nseg);

    const int gblocks = (nseg + 63) / 64;
    gemm_qk_merged<<<gblocks, 256, 0, stream>>>(user_embed, item_embed,
                                                Wq, bq, Wk, bk, QK, U, I, D);

    const int eblocks = (int)(((long long)E * 32 + 255) / 256);
    edge_w_both<<<eblocks, 256, 0, stream>>>(QK, ui_rows, ui_cols,
                                             noise_ui, noise_iu,
                                             out, seg_max, U, E);

    if ((E & 1) == 0) {
        const int vblocks = (E + 255) / 256;   // E pairs cover 2E elements
        edge_exp2v<<<vblocks, 256, 0, stream>>>(out, ui_rows, ui_cols,
                                                seg_max, seg_sum, U, E);
        edge_norm2v<<<vblocks, 256, 0, stream>>>(out, ui_rows, ui_cols,
                                                 seg_sum, U, E);
    } else {
        const int sblocks = (2 * E + 255) / 256;
        edge_exp2<<<sblocks, 256, 0, stream>>>(out, ui_rows, ui_cols,
                                               seg_max, seg_sum, U, E);
        edge_norm2<<<sblocks, 256, 0, stream>>>(out, ui_rows, ui_cols,
                                                seg_sum, U, E);
    }
}

// Round 3
// 475.350 us; speedup vs baseline: 1.4883x; 1.4767x over previous
//
#include <hip/hip_runtime.h>
#include <hip/hip_fp16.h>
#include <math.h>

#define TAU_INV 5.0f      // 1 / 0.2
#define LOG2E   1.4426950408889634f

typedef _Float16 half2v __attribute__((ext_vector_type(2)));

// raw gfx950 transcendentals: v_exp_f32 is 2^x, v_log_f32 is log2(x)
__device__ __forceinline__ float fast_exp2(float x) { return __builtin_amdgcn_exp2f(x); }
__device__ __forceinline__ float fast_log2(float x) { return __builtin_amdgcn_logf(x); }

// ---------------------------------------------------------------------------
__global__ void init_sumd(double* __restrict__ seg_sumd, int n) {
    int i = blockIdx.x * blockDim.x + threadIdx.x;
    if (i < n) seg_sumd[i] = 0.0;
}

// exp(z) as a double, via 2^n * exp2(r).  z in ~[-700, +700] is safe.
__device__ __forceinline__ double exp_double(float z) {
    float y = z * LOG2E;
    float n = rintf(y);
    float r = y - n;                 // |r| <= 0.5
    float f = fast_exp2(r);
    long long e = (long long)n + 1023;
    if (e < 1)    e = 1;             // clamp: astronomically small, irrelevant
    if (e > 2046) e = 2046;          // clamp: cannot happen for this data
    double scale = __longlong_as_double(e << 52);
    return (double)f * scale;
}

// log2 of a positive normal double, to float precision.
__device__ __forceinline__ float log2_of_double(double v) {
    unsigned long long b = __double_as_longlong(v);
    int ex = (int)((b >> 52) & 0x7FFULL) - 1023;
    double m = __longlong_as_double((b & 0xFFFFFFFFFFFFFULL) | 0x3FF0000000000000ULL);
    return (float)ex + fast_log2((float)m);
}

// ---------------------------------------------------------------------------
// Merged fp32 GEMM (R5 structure — known 147 us; do NOT hand-pipeline: R4's
// serial register stream and R6's cross-barrier prefetch regs both lost).
// X = [Xu; Xi] (75000 x 256); Q = X@Wq+bq, K = X@Wk+bk; A staged once.
// Epilogue: fp16 INTERLEAVED rows  QK[gr*256 + 0..127] = Q, [128..255] = K.
// ---------------------------------------------------------------------------
__global__ __launch_bounds__(256) void gemm_qk_merged(
    const float* __restrict__ Xu, const float* __restrict__ Xi,
    const float* __restrict__ Wq, const float* __restrict__ bq,
    const float* __restrict__ Wk, const float* __restrict__ bk,
    __half* __restrict__ QK,
    int U, int I, int D)
{
    __shared__ float As_t[16][68];
    __shared__ float Bs_q[16][132];
    __shared__ float Bs_k[16][132];

    const int tid  = threadIdx.x;
    const int row0 = blockIdx.x * 64;
    const int tr   = tid >> 5;
    const int tc   = tid & 31;

    float4 accq[8], acck[8];
#pragma unroll
    for (int i = 0; i < 8; ++i) {
        accq[i] = make_float4(0.f, 0.f, 0.f, 0.f);
        acck[i] = make_float4(0.f, 0.f, 0.f, 0.f);
    }

    const int ar  = tid >> 2;
    const int akq = (tid & 3) * 4;

    for (int k0 = 0; k0 < D; k0 += 16) {
        {
            int gr = row0 + ar;
            float4 v = make_float4(0.f, 0.f, 0.f, 0.f);
            if (gr < U)            v = *(const float4*)&Xu[(size_t)gr * D + k0 + akq];
            else if (gr - U < I)   v = *(const float4*)&Xi[(size_t)(gr - U) * D + k0 + akq];
            As_t[akq + 0][ar] = v.x;
            As_t[akq + 1][ar] = v.y;
            As_t[akq + 2][ar] = v.z;
            As_t[akq + 3][ar] = v.w;
        }
#pragma unroll
        for (int t = 0; t < 2; ++t) {
            int idx = tid + t * 256;
            int r  = idx >> 5;
            int c4 = (idx & 31) * 4;
            float4 vq = *(const float4*)&Wq[(size_t)(k0 + r) * 128 + c4];
            float4 vk = *(const float4*)&Wk[(size_t)(k0 + r) * 128 + c4];
            *(float4*)&Bs_q[r][c4] = vq;
            *(float4*)&Bs_k[r][c4] = vk;
        }
        __syncthreads();

#pragma unroll
        for (int kk = 0; kk < 16; ++kk) {
            float4 a0  = *(const float4*)&As_t[kk][tr * 8];
            float4 a1  = *(const float4*)&As_t[kk][tr * 8 + 4];
            float4 bqv = *(const float4*)&Bs_q[kk][tc * 4];
            float4 bkv = *(const float4*)&Bs_k[kk][tc * 4];
            float a[8] = {a0.x, a0.y, a0.z, a0.w, a1.x, a1.y, a1.z, a1.w};
#pragma unroll
            for (int i = 0; i < 8; ++i) {
                accq[i].x += a[i] * bqv.x;
                accq[i].y += a[i] * bqv.y;
                accq[i].z += a[i] * bqv.z;
                accq[i].w += a[i] * bqv.w;
                acck[i].x += a[i] * bkv.x;
                acck[i].y += a[i] * bkv.y;
                acck[i].z += a[i] * bkv.z;
                acck[i].w += a[i] * bkv.w;
            }
        }
        __syncthreads();
    }

    const float4 bbq = *(const float4*)&bq[tc * 4];
    const float4 bbk = *(const float4*)&bk[tc * 4];
    const int NT = U + I;
#pragma unroll
    for (int i = 0; i < 8; ++i) {
        int gr = row0 + tr * 8 + i;
        if (gr < NT) {
            __half2 q01 = __floats2half2_rn(accq[i].x + bbq.x, accq[i].y + bbq.y);
            __half2 q23 = __floats2half2_rn(accq[i].z + bbq.z, accq[i].w + bbq.w);
            __half2 k01 = __floats2half2_rn(acck[i].x + bbk.x, acck[i].y + bbk.y);
            __half2 k23 = __floats2half2_rn(acck[i].z + bbk.z, acck[i].w + bbk.w);
            uint2 pq, pk;
            pq.x = *(const unsigned int*)&q01;
            pq.y = *(const unsigned int*)&q23;
            pk.x = *(const unsigned int*)&k01;
            pk.y = *(const unsigned int*)&k23;
            *(uint2*)&QK[(size_t)gr * 256 + tc * 4]       = pq;   // Q half
            *(uint2*)&QK[(size_t)gr * 256 + 128 + tc * 4] = pk;   // K half
        }
    }
}

// ---------------------------------------------------------------------------
// Fused BOTH-direction edge kernel, 16 lanes per edge.
// Each lane loads 4 x 16B:  Q_user, K_item (dir ui)  and  Q_item, K_user (iu).
// Dual fdot2 accumulators, dual butterfly reduce over the 16-lane group;
// lanes 0 and 1 then handle the ui / iu tails in parallel:
//   z = (d - log(-log(noise))) / tau ; store z ; atomicAdd seg_sumd += exp(z)
// (no max pass: softmax is shift-invariant; the double accumulator absorbs
//  the dynamic range, and the norm pass works in log2 domain).
// ---------------------------------------------------------------------------
__global__ __launch_bounds__(256) void edge_w_both(
    const __half* __restrict__ QK,
    const int* __restrict__ rows, const int* __restrict__ cols,
    const float* __restrict__ noise_ui, const float* __restrict__ noise_iu,
    float* __restrict__ out, double* __restrict__ seg_sumd, int U, int E)
{
    const int gtid = blockIdx.x * 256 + threadIdx.x;
    const int eid  = gtid >> 4;
    if (eid >= E) return;
    const int hl = threadIdx.x & 15;

    const int r = rows[eid];
    const int c = cols[eid];
    const __half* urow = QK + (size_t)r * 256;
    const __half* irow = QK + (size_t)(U + c) * 256;

    const uint4 qu = *(const uint4*)(urow + hl * 8);         // Q_user
    const uint4 ki = *(const uint4*)(irow + 128 + hl * 8);   // K_item
    const uint4 qi = *(const uint4*)(irow + hl * 8);         // Q_item
    const uint4 ku = *(const uint4*)(urow + 128 + hl * 8);   // K_user

    float d0 = 0.0f, d1 = 0.0f;
    {
        const half2v* a0 = (const half2v*)&qu;
        const half2v* b0 = (const half2v*)&ki;
        const half2v* a1 = (const half2v*)&qi;
        const half2v* b1 = (const half2v*)&ku;
#pragma unroll
        for (int t = 0; t < 4; ++t) {
            d0 = __builtin_amdgcn_fdot2(a0[t], b0[t], d0, false);
            d1 = __builtin_amdgcn_fdot2(a1[t], b1[t], d1, false);
        }
    }
    d0 += __shfl_xor(d0, 8);  d1 += __shfl_xor(d1, 8);
    d0 += __shfl_xor(d0, 4);  d1 += __shfl_xor(d1, 4);
    d0 += __shfl_xor(d0, 2);  d1 += __shfl_xor(d1, 2);
    d0 += __shfl_xor(d0, 1);  d1 += __shfl_xor(d1, 1);

    if (hl < 2) {
        const int g  = hl;                      // 0 = ui, 1 = iu
        const float d  = g ? d1 : d0;
        const float nz = g ? noise_iu[eid] : noise_ui[eid];
        const float zz = (d - __logf(-__logf(nz))) * TAU_INV;
        const int s  = g ? (U + c) : r;
        out[(size_t)g * E + eid] = zz;
        atomicAdd(&seg_sumd[s], exp_double(zz));
    }
}

// ---------------------------------------------------------------------------
// out = exp(z) / S[seg]  computed as  exp2(z*log2e - log2(S))  (all float,
// no overflow since the argument is <= ~0).  Vectorized 2 elems/thread.
// ---------------------------------------------------------------------------
__global__ void edge_norm2v(float* __restrict__ z,
                            const int* __restrict__ rows, const int* __restrict__ cols,
                            const double* __restrict__ seg_sumd, int U, int E)
{
    int p = blockIdx.x * blockDim.x + threadIdx.x;
    int i = p * 2;
    if (i >= 2 * E) return;
    const bool iu  = (i >= E);
    const int base = iu ? (i - E) : i;
    const int off  = iu ? U : 0;
    const int* idx = iu ? cols : rows;
    int2 rc   = *(const int2*)&idx[base];
    float2 zz = *(const float2*)&z[i];
    float l0 = log2_of_double(seg_sumd[off + rc.x]);
    float l1 = log2_of_double(seg_sumd[off + rc.y]);
    float o0 = fast_exp2(zz.x * LOG2E - l0);
    float o1 = fast_exp2(zz.y * LOG2E - l1);
    *(float2*)&z[i] = make_float2(o0, o1);
}

__global__ void edge_norm2(float* __restrict__ z,
                           const int* __restrict__ rows, const int* __restrict__ cols,
                           const double* __restrict__ seg_sumd, int U, int E)
{
    int i = blockIdx.x * blockDim.x + threadIdx.x;
    if (i >= 2 * E) return;
    int s = (i < E) ? rows[i] : (U + cols[i - E]);
    float l = log2_of_double(seg_sumd[s]);
    z[i] = fast_exp2(z[i] * LOG2E - l);
}

// ---------------------------------------------------------------------------
extern "C" void kernel_launch(void* const* d_in, const int* in_sizes, int n_in,
                              void* d_out, int out_size, void* d_ws, size_t ws_size,
                              hipStream_t stream)
{
    const float* user_embed = (const float*)d_in[0];
    const float* item_embed = (const float*)d_in[1];
    const float* Wq = (const float*)d_in[2];
    const float* bq = (const float*)d_in[3];
    const float* Wk = (const float*)d_in[4];
    const float* bk = (const float*)d_in[5];
    const int* ui_rows    = (const int*)d_in[6];
    const int* ui_cols    = (const int*)d_in[7];
    const float* noise_ui = (const float*)d_in[8];
    const float* noise_iu = (const float*)d_in[9];

    const int H = in_sizes[3];           // 128
    const int D = in_sizes[2] / H;       // 256
    const int U = in_sizes[0] / D;       // 50000
    const int I = in_sizes[1] / D;       // 25000
    const int E = in_sizes[6];           // 1600000

    const int nseg = U + I;

    // workspace: QK (fp16 interleaved, (U+I) x 256) | seg_sumd (double)
    char* wsc = (char*)d_ws;
    __half* QK = (__half*)wsc;        wsc += (size_t)nseg * 256 * sizeof(__half);
    double* seg_sumd = (double*)wsc;  wsc += (size_t)nseg * sizeof(double);

    float* out = (float*)d_out;       // [z_ui | z_iu] -> normalized in place

    init_sumd<<<(nseg + 255) / 256, 256, 0, stream>>>(seg_sumd, nseg);

    const int gblocks = (nseg + 63) / 64;
    gemm_qk_merged<<<gblocks, 256, 0, stream>>>(user_embed, item_embed,
                                                Wq, bq, Wk, bk, QK, U, I, D);

    const int eblocks = (int)(((long long)E * 16 + 255) / 256);
    edge_w_both<<<eblocks, 256, 0, stream>>>(QK, ui_rows, ui_cols,
                                             noise_ui, noise_iu,
                                             out, seg_sumd, U, E);

    if ((E & 1) == 0) {
        const int vblocks = (E + 255) / 256;   // E pairs cover 2E elements
        edge_norm2v<<<vblocks, 256, 0, stream>>>(out, ui_rows, ui_cols,
                                                 seg_sumd, U, E);
    } else {
        const int sblocks = (2 * E + 255) / 256;
        edge_norm2<<<sblocks, 256, 0, stream>>>(out, ui_rows, ui_cols,
                                                seg_sumd, U, E);
    }
}